// Round 1
// baseline (1720.672 us; speedup 1.0000x reference)
//
#include <hip/hip_runtime.h>
#include <hip/hip_bf16.h>
#include <math.h>

// Problem constants
#define BB 4
#define C_IN 256
#define HH 256
#define WW 256
#define LL 5000
#define N_PTS0 32
#define N_PTS1 8
#define DIM_LOI 128
#define DIM_FC 1024
#define N_OUT_LINE 2500
#define MM (BB * LL)          // 20000
#define PIX (HH * WW)         // 65536

// ---------------------------------------------------------------------------
// Kernel 1: 1x1 conv as GEMM-TN.  x[b,p,o] = sum_c feat[b,c,p] * w[o,c] + bias[o]
// Output NHWC so the sampler gathers 128 contiguous channels per pixel.
// Grid: (B*PIX/128) = 2048 blocks x 256 threads. BM=128 pixels, BN=128 outs, BK=16.
// ---------------------------------------------------------------------------
__global__ __launch_bounds__(256) void conv1x1_kernel(
    const float* __restrict__ feat,   // [B, 256, PIX]
    const float* __restrict__ w,      // [128, 256]
    const float* __restrict__ bias,   // [128]
    float* __restrict__ x)            // [B*PIX, 128]
{
    __shared__ float As[16][128];     // [k][pixel]
    __shared__ float Ws[16][128];     // [k][o]
    const int t = threadIdx.x;
    const int m0 = blockIdx.x * 128;            // global pixel-row
    const int b  = m0 >> 16;
    const int p0 = m0 & (PIX - 1);
    const float* fb = feat + (size_t)b * C_IN * PIX + p0;

    const int q = (t & 15) * 4;   // A sub-row base, rows q..q+3 and q+64..q+67
    const int r = (t >> 4) * 4;   // B sub-col base

    float acc[8][8];
#pragma unroll
    for (int i = 0; i < 8; i++)
#pragma unroll
        for (int j = 0; j < 8; j++) acc[i][j] = 0.0f;

    for (int k0 = 0; k0 < C_IN; k0 += 16) {
        // A tile: 16 rows(k) x 128 pixels, contiguous along pixels
#pragma unroll
        for (int i = 0; i < 2; i++) {
            int idx  = t + i * 256;          // 0..511
            int krow = idx >> 5;             // 0..15
            int m4   = (idx & 31) * 4;       // 0..124
            float4 v = *(const float4*)(fb + (size_t)(k0 + krow) * PIX + m4);
            *(float4*)&As[krow][m4] = v;
        }
        // W tile: transpose-on-store
#pragma unroll
        for (int i = 0; i < 2; i++) {
            int idx = t + i * 256;
            int o   = idx >> 2;              // 0..127
            int cq  = (idx & 3) * 4;
            float4 v = *(const float4*)(w + o * C_IN + k0 + cq);
            Ws[cq + 0][o] = v.x; Ws[cq + 1][o] = v.y;
            Ws[cq + 2][o] = v.z; Ws[cq + 3][o] = v.w;
        }
        __syncthreads();
#pragma unroll
        for (int k = 0; k < 16; k++) {
            float4 a0 = *(const float4*)&As[k][q];
            float4 a1 = *(const float4*)&As[k][q + 64];
            float4 b0 = *(const float4*)&Ws[k][r];
            float4 b1 = *(const float4*)&Ws[k][r + 64];
            float a[8] = {a0.x, a0.y, a0.z, a0.w, a1.x, a1.y, a1.z, a1.w};
            float bb[8] = {b0.x, b0.y, b0.z, b0.w, b1.x, b1.y, b1.z, b1.w};
#pragma unroll
            for (int i = 0; i < 8; i++)
#pragma unroll
                for (int j = 0; j < 8; j++)
                    acc[i][j] = fmaf(a[i], bb[j], acc[i][j]);
        }
        __syncthreads();
    }
    // epilogue: add bias, store NHWC
#pragma unroll
    for (int jh = 0; jh < 2; jh++) {
        int n = r + jh * 64;
        float4 bv = *(const float4*)(bias + n);
#pragma unroll
        for (int i = 0; i < 8; i++) {
            int m = m0 + q + (i & 3) + ((i >> 2) << 6);
            float4 v;
            v.x = acc[i][jh * 4 + 0] + bv.x;
            v.y = acc[i][jh * 4 + 1] + bv.y;
            v.z = acc[i][jh * 4 + 2] + bv.z;
            v.w = acc[i][jh * 4 + 3] + bv.w;
            *(float4*)(x + (size_t)m * 128 + n) = v;
        }
    }
}

// ---------------------------------------------------------------------------
// Kernel 2: bilinear sample 32 pts/line from NHWC x, maxpool groups of 4.
// One block (128 threads = channels) per line.
// pooled[(b*L+l)*1024 + c*8 + g]
// ---------------------------------------------------------------------------
__global__ __launch_bounds__(128) void sample_pool_kernel(
    const float* __restrict__ lines,   // [B, L, 2, 2]
    const float* __restrict__ x,       // [B*PIX, 128] NHWC
    float* __restrict__ pooled)        // [B*L, 1024]
{
    const int bl = blockIdx.x;
    const int b  = bl / LL;
    const int c  = threadIdx.x;
    const float* lp = lines + (size_t)bl * 4;
    const float p0r = lp[0], p0c = lp[1], p1r = lp[2], p1c = lp[3];
    const float* xb = x + (size_t)b * PIX * 128;
    float* outp = pooled + (size_t)bl * 1024 + c * 8;

    for (int g = 0; g < 8; g++) {
        float mx = -INFINITY;
#pragma unroll
        for (int j = 0; j < 4; j++) {
            int tt = g * 4 + j;
            float lam = (float)((double)tt / 31.0);
            float px = p0r * lam + p1r * (1.0f - lam) - 0.5f;
            float py = p0c * lam + p1c * (1.0f - lam) - 0.5f;
            float px0 = fminf(fmaxf(floorf(px), 0.0f), 255.0f);
            float py0 = fminf(fmaxf(floorf(py), 0.0f), 255.0f);
            float px1 = fminf(px0 + 1.0f, 255.0f);
            float py1 = fminf(py0 + 1.0f, 255.0f);
            int ix0 = (int)px0, iy0 = (int)py0, ix1 = (int)px1, iy1 = (int)py1;
            float wx1 = px1 - px, wx0 = px - px0;
            float wy1 = py1 - py, wy0 = py - py0;
            float v00 = xb[(size_t)(ix0 * WW + iy0) * 128 + c];
            float v10 = xb[(size_t)(ix1 * WW + iy0) * 128 + c];
            float v01 = xb[(size_t)(ix0 * WW + iy1) * 128 + c];
            float v11 = xb[(size_t)(ix1 * WW + iy1) * 128 + c];
            float v = v00 * (wx1 * wy1) + v10 * (wx0 * wy1)
                    + v01 * (wx1 * wy0) + v11 * (wx0 * wy0);
            mx = fmaxf(mx, v);
        }
        outp[g] = mx;
    }
}

// ---------------------------------------------------------------------------
// Kernel 3: fp32 GEMM-NT with fused bias+ReLU.  C[M,N] = act(A[M,K] B[N,K]^T + bias)
// 128x128 tile, BK=16, 8x8 microtile with +-64 split (2-way LDS aliasing = free).
// ---------------------------------------------------------------------------
template <bool RELU>
__global__ __launch_bounds__(256) void gemm_nt(
    const float* __restrict__ A, const float* __restrict__ Bm,
    const float* __restrict__ bias, float* __restrict__ C,
    int M, int N, int K)
{
    __shared__ float As[16][128];
    __shared__ float Bs[16][128];
    const int t = threadIdx.x;
    const int ntiles = N >> 7;
    const int tileN = blockIdx.x % ntiles;
    const int tileM = blockIdx.x / ntiles;
    const int m0 = tileM * 128, n0 = tileN * 128;

    const int q = (t & 15) * 4;
    const int r = (t >> 4) * 4;

    float acc[8][8];
#pragma unroll
    for (int i = 0; i < 8; i++)
#pragma unroll
        for (int j = 0; j < 8; j++) acc[i][j] = 0.0f;

    for (int k0 = 0; k0 < K; k0 += 16) {
#pragma unroll
        for (int i = 0; i < 2; i++) {
            int idx = t + i * 256;
            int m   = idx & 127;
            int kq  = (idx >> 7) * 4;
            int row = m0 + m; row = row < M ? row : M - 1;   // clamp (stores guarded)
            float4 v = *(const float4*)(A + (size_t)row * K + k0 + kq);
            As[kq + 0][m] = v.x; As[kq + 1][m] = v.y;
            As[kq + 2][m] = v.z; As[kq + 3][m] = v.w;
        }
#pragma unroll
        for (int i = 0; i < 2; i++) {
            int idx = t + i * 256;
            int n   = idx & 127;
            int kq  = (idx >> 7) * 4;
            float4 v = *(const float4*)(Bm + (size_t)(n0 + n) * K + k0 + kq);
            Bs[kq + 0][n] = v.x; Bs[kq + 1][n] = v.y;
            Bs[kq + 2][n] = v.z; Bs[kq + 3][n] = v.w;
        }
        __syncthreads();
#pragma unroll
        for (int k = 0; k < 16; k++) {
            float4 a0 = *(const float4*)&As[k][q];
            float4 a1 = *(const float4*)&As[k][q + 64];
            float4 b0 = *(const float4*)&Bs[k][r];
            float4 b1 = *(const float4*)&Bs[k][r + 64];
            float a[8] = {a0.x, a0.y, a0.z, a0.w, a1.x, a1.y, a1.z, a1.w};
            float bb[8] = {b0.x, b0.y, b0.z, b0.w, b1.x, b1.y, b1.z, b1.w};
#pragma unroll
            for (int i = 0; i < 8; i++)
#pragma unroll
                for (int j = 0; j < 8; j++)
                    acc[i][j] = fmaf(a[i], bb[j], acc[i][j]);
        }
        __syncthreads();
    }
#pragma unroll
    for (int jh = 0; jh < 2; jh++) {
        int n = n0 + r + jh * 64;
        float4 bv = *(const float4*)(bias + n);
#pragma unroll
        for (int i = 0; i < 8; i++) {
            int m = m0 + q + (i & 3) + ((i >> 2) << 6);
            if (m < M) {
                float4 v;
                v.x = acc[i][jh * 4 + 0] + bv.x;
                v.y = acc[i][jh * 4 + 1] + bv.y;
                v.z = acc[i][jh * 4 + 2] + bv.z;
                v.w = acc[i][jh * 4 + 3] + bv.w;
                if (RELU) {
                    v.x = fmaxf(v.x, 0.0f); v.y = fmaxf(v.y, 0.0f);
                    v.z = fmaxf(v.z, 0.0f); v.w = fmaxf(v.w, 0.0f);
                }
                *(float4*)(C + (size_t)m * N + n) = v;
            }
        }
    }
}

// ---------------------------------------------------------------------------
// Kernel 4: fc3 (N=4) + softmax + mask + argmax-class key. One wave per line.
// ---------------------------------------------------------------------------
__global__ __launch_bounds__(256) void fc3_softmax_kernel(
    const float* __restrict__ h2, const float* __restrict__ w3,
    const float* __restrict__ b3, float* __restrict__ s, int* __restrict__ keys)
{
    const int m = blockIdx.x * 4 + (threadIdx.x >> 6);
    const int lane = threadIdx.x & 63;
    const float* hp = h2 + (size_t)m * DIM_FC;
    float a0 = 0.f, a1 = 0.f, a2 = 0.f, a3 = 0.f;
    for (int k = lane; k < DIM_FC; k += 64) {
        float hv = hp[k];
        a0 = fmaf(hv, w3[k], a0);
        a1 = fmaf(hv, w3[DIM_FC + k], a1);
        a2 = fmaf(hv, w3[2 * DIM_FC + k], a2);
        a3 = fmaf(hv, w3[3 * DIM_FC + k], a3);
    }
#pragma unroll
    for (int off = 32; off > 0; off >>= 1) {
        a0 += __shfl_down(a0, off, 64);
        a1 += __shfl_down(a1, off, 64);
        a2 += __shfl_down(a2, off, 64);
        a3 += __shfl_down(a3, off, 64);
    }
    if (lane == 0) {
        float l0 = a0 + b3[0], l1 = a1 + b3[1], l2 = a2 + b3[2], l3 = a3 + b3[3];
        float mxl = fmaxf(fmaxf(l0, l1), fmaxf(l2, l3));
        float e0 = expf(l0 - mxl), e1 = expf(l1 - mxl);
        float e2 = expf(l2 - mxl), e3 = expf(l3 - mxl);
        float inv = 1.0f / (e0 + e1 + e2 + e3);
        float s0 = e0 * inv, s1 = e1 * inv, s2 = e2 * inv, s3 = e3 * inv;
        float* sp = s + (size_t)m * 4;
        sp[0] = s0; sp[1] = s1; sp[2] = s2; sp[3] = s3;
        int best = 0; float bv = s0;
        if (s1 > bv) { best = 1; bv = s1; }
        if (s2 > bv) { best = 2; bv = s2; }
        if (s3 > bv) { best = 3; bv = s3; }
        bool msk = ((s1 > 0.25f) || (s2 > 0.25f) || (s3 > 0.25f)) && (s0 < 0.25f);
        keys[m] = msk ? best : -1;
    }
}

// ---------------------------------------------------------------------------
// Kernel 5: stable counting sort by class descending (replicates stable
// argsort(-key)). One wave per batch image.
// ---------------------------------------------------------------------------
__global__ __launch_bounds__(64) void order_kernel(
    const int* __restrict__ keys, int* __restrict__ ord, int* __restrict__ cnts)
{
    const int b = blockIdx.x;
    const int lane = threadIdx.x;
    const int* kb = keys + b * LL;
    int c0 = 0, c1 = 0, c2 = 0, c3 = 0;
    for (int line = lane; line < LL; line += 64) {
        int k = kb[line];
        c0 += (k == 0); c1 += (k == 1); c2 += (k == 2); c3 += (k == 3);
    }
#pragma unroll
    for (int off = 32; off > 0; off >>= 1) {
        c0 += __shfl_down(c0, off, 64);
        c1 += __shfl_down(c1, off, 64);
        c2 += __shfl_down(c2, off, 64);
        c3 += __shfl_down(c3, off, 64);
    }
    int t0 = __shfl(c0, 0, 64), t1 = __shfl(c1, 0, 64);
    int t2 = __shfl(c2, 0, 64), t3 = __shfl(c3, 0, 64);
    if (lane == 0) cnts[b] = t0 + t1 + t2 + t3;
    int base[4];
    base[3] = 0; base[2] = t3; base[1] = t3 + t2; base[0] = t3 + t2 + t1;
    int run[4] = {0, 0, 0, 0};
    const unsigned long long below = (1ull << lane) - 1ull;
    int* ob = ord + b * LL;
    for (int s0 = 0; s0 < LL; s0 += 64) {
        int line = s0 + lane;
        int k = (line < LL) ? kb[line] : -2;
#pragma unroll
        for (int kk = 0; kk < 4; kk++) {
            unsigned long long mask = __ballot(k == kk);
            if (k == kk) {
                int pos = base[kk] + run[kk] + __popcll(mask & below);
                ob[pos] = line;
            }
            run[kk] += __popcll(mask);
        }
    }
}

// ---------------------------------------------------------------------------
// Kernel 6: cyclic fill of 2500 outputs per batch.
// out[0:40000) = lines_out, out[40000:80000) = score_out
// ---------------------------------------------------------------------------
__global__ __launch_bounds__(256) void fill_kernel(
    const float* __restrict__ lines, const float* __restrict__ s,
    const int* __restrict__ ord, const int* __restrict__ cnts,
    float* __restrict__ out)
{
    const int i = blockIdx.x * 256 + threadIdx.x;
    if (i >= BB * N_OUT_LINE) return;
    const int b = i / N_OUT_LINE;
    const int j = i % N_OUT_LINE;
    const int cnt = cnts[b];
    float4 lo = {0.f, 0.f, 0.f, 0.f}, sc = {0.f, 0.f, 0.f, 0.f};
    if (cnt > 0) {
        int line = ord[b * LL + (j % cnt)];
        lo = *(const float4*)(lines + ((size_t)b * LL + line) * 4);
        sc = *(const float4*)(s + ((size_t)b * LL + line) * 4);
    }
    *(float4*)(out + (size_t)i * 4) = lo;
    *(float4*)(out + (size_t)(BB * N_OUT_LINE) * 4 + (size_t)i * 4) = sc;
}

// ---------------------------------------------------------------------------
extern "C" void kernel_launch(void* const* d_in, const int* in_sizes, int n_in,
                              void* d_out, int out_size, void* d_ws, size_t ws_size,
                              hipStream_t stream) {
    (void)in_sizes; (void)n_in; (void)out_size; (void)ws_size;
    const float* feature = (const float*)d_in[0];
    const float* lines   = (const float*)d_in[1];
    const float* fc1_w   = (const float*)d_in[2];
    const float* fc1_b   = (const float*)d_in[3];
    const float* w1      = (const float*)d_in[4];
    const float* b1      = (const float*)d_in[5];
    const float* w2      = (const float*)d_in[6];
    const float* b2      = (const float*)d_in[7];
    const float* w3      = (const float*)d_in[8];
    const float* b3      = (const float*)d_in[9];
    float* out = (float*)d_out;

    // workspace layout (bytes): x 128MB | pooled 78.1MB | s 320KB | keys/ord/cnts
    // h1 aliases x (dead after sampling); h2 aliases pooled (dead after h1 GEMM).
    float* x      = (float*)d_ws;                    // 33,554,432 floats
    float* pooled = x + (size_t)BB * PIX * 128;      // 20,480,000 floats
    float* h1     = x;
    float* h2     = pooled;
    float* s      = pooled + (size_t)MM * DIM_FC;    // 80,000 floats
    int*   keys   = (int*)(s + MM * 4);              // 20,000 ints
    int*   ord    = keys + MM;                       // 20,000 ints
    int*   cnts   = ord + MM;                        // 4 ints

    conv1x1_kernel<<<(BB * PIX) / 128, 256, 0, stream>>>(feature, fc1_w, fc1_b, x);
    sample_pool_kernel<<<MM, 128, 0, stream>>>(lines, x, pooled);
    const int mtiles = (MM + 127) / 128;             // 157
    gemm_nt<true><<<mtiles * (DIM_FC / 128), 256, 0, stream>>>(
        pooled, w1, b1, h1, MM, DIM_FC, DIM_FC);
    gemm_nt<true><<<mtiles * (DIM_FC / 128), 256, 0, stream>>>(
        h1, w2, b2, h2, MM, DIM_FC, DIM_FC);
    fc3_softmax_kernel<<<MM / 4, 256, 0, stream>>>(h2, w3, b3, s, keys);
    order_kernel<<<BB, 64, 0, stream>>>(keys, ord, cnts);
    fill_kernel<<<(BB * N_OUT_LINE + 255) / 256, 256, 0, stream>>>(
        lines, s, ord, cnts, out);
}

// Round 2
// 1066.018 us; speedup vs baseline: 1.6141x; 1.6141x over previous
//
#include <hip/hip_runtime.h>
#include <hip/hip_bf16.h>
#include <math.h>

// Problem constants
#define BB 4
#define C_IN 256
#define HH 256
#define WW 256
#define LL 5000
#define N_PTS0 32
#define N_PTS1 8
#define DIM_LOI 128
#define DIM_FC 1024
#define N_OUT_LINE 2500
#define MM (BB * LL)          // 20000
#define PIX (HH * WW)         // 65536

typedef __attribute__((ext_vector_type(8))) short short8_t;   // 8 bf16 in 4 VGPRs
typedef __attribute__((ext_vector_type(4))) float float4v;

// float -> bf16 (RNE) bit tricks
__device__ __forceinline__ short f2bf(float f) {
    union { float f; unsigned u; } c; c.f = f;
    unsigned u = c.u;
    u += 0x7FFFu + ((u >> 16) & 1u);
    return (short)(u >> 16);
}
__device__ __forceinline__ float bf2f(short h) {
    union { unsigned u; float f; } c; c.u = ((unsigned)(unsigned short)h) << 16;
    return c.f;
}

// ---------------------------------------------------------------------------
// Kernel 1: 1x1 conv as GEMM-TN (fp32 vector). Output NHWC x[b*PIX+p][128].
// ---------------------------------------------------------------------------
__global__ __launch_bounds__(256) void conv1x1_kernel(
    const float* __restrict__ feat,   // [B, 256, PIX]
    const float* __restrict__ w,      // [128, 256]
    const float* __restrict__ bias,   // [128]
    float* __restrict__ x)            // [B*PIX, 128]
{
    __shared__ float As[16][128];     // [k][pixel]
    __shared__ float Ws[16][128];     // [k][o]
    const int t = threadIdx.x;
    const int m0 = blockIdx.x * 128;
    const int b  = m0 >> 16;
    const int p0 = m0 & (PIX - 1);
    const float* fb = feat + (size_t)b * C_IN * PIX + p0;

    const int q = (t & 15) * 4;
    const int r = (t >> 4) * 4;

    float acc[8][8];
#pragma unroll
    for (int i = 0; i < 8; i++)
#pragma unroll
        for (int j = 0; j < 8; j++) acc[i][j] = 0.0f;

    for (int k0 = 0; k0 < C_IN; k0 += 16) {
#pragma unroll
        for (int i = 0; i < 2; i++) {
            int idx  = t + i * 256;
            int krow = idx >> 5;
            int m4   = (idx & 31) * 4;
            float4 v = *(const float4*)(fb + (size_t)(k0 + krow) * PIX + m4);
            *(float4*)&As[krow][m4] = v;
        }
#pragma unroll
        for (int i = 0; i < 2; i++) {
            int idx = t + i * 256;
            int o   = idx >> 2;
            int cq  = (idx & 3) * 4;
            float4 v = *(const float4*)(w + o * C_IN + k0 + cq);
            Ws[cq + 0][o] = v.x; Ws[cq + 1][o] = v.y;
            Ws[cq + 2][o] = v.z; Ws[cq + 3][o] = v.w;
        }
        __syncthreads();
#pragma unroll
        for (int k = 0; k < 16; k++) {
            float4 a0 = *(const float4*)&As[k][q];
            float4 a1 = *(const float4*)&As[k][q + 64];
            float4 b0 = *(const float4*)&Ws[k][r];
            float4 b1 = *(const float4*)&Ws[k][r + 64];
            float a[8] = {a0.x, a0.y, a0.z, a0.w, a1.x, a1.y, a1.z, a1.w};
            float bb[8] = {b0.x, b0.y, b0.z, b0.w, b1.x, b1.y, b1.z, b1.w};
#pragma unroll
            for (int i = 0; i < 8; i++)
#pragma unroll
                for (int j = 0; j < 8; j++)
                    acc[i][j] = fmaf(a[i], bb[j], acc[i][j]);
        }
        __syncthreads();
    }
#pragma unroll
    for (int jh = 0; jh < 2; jh++) {
        int n = r + jh * 64;
        float4 bv = *(const float4*)(bias + n);
#pragma unroll
        for (int i = 0; i < 8; i++) {
            int m = m0 + q + (i & 3) + ((i >> 2) << 6);
            float4 v;
            v.x = acc[i][jh * 4 + 0] + bv.x;
            v.y = acc[i][jh * 4 + 1] + bv.y;
            v.z = acc[i][jh * 4 + 2] + bv.z;
            v.w = acc[i][jh * 4 + 3] + bv.w;
            *(float4*)(x + (size_t)m * 128 + n) = v;
        }
    }
}

// ---------------------------------------------------------------------------
// Kernel 2: bilinear sample + maxpool. Emits bf16 hi/lo split of pooled
// features (hi+lo reconstructs to ~2^-17 relative — feeds bf16x3 GEMM).
// ---------------------------------------------------------------------------
__global__ __launch_bounds__(128) void sample_pool_kernel(
    const float* __restrict__ lines,   // [B, L, 2, 2]
    const float* __restrict__ x,       // [B*PIX, 128] NHWC
    short* __restrict__ phi,           // [B*L, 1024] bf16 hi
    short* __restrict__ plo)           // [B*L, 1024] bf16 lo
{
    const int bl = blockIdx.x;
    const int b  = bl / LL;
    const int c  = threadIdx.x;
    const float* lp = lines + (size_t)bl * 4;
    const float p0r = lp[0], p0c = lp[1], p1r = lp[2], p1c = lp[3];
    const float* xb = x + (size_t)b * PIX * 128;

    short8_t vh, vl;
#pragma unroll
    for (int g = 0; g < 8; g++) {
        float mx = -INFINITY;
#pragma unroll
        for (int j = 0; j < 4; j++) {
            int tt = g * 4 + j;
            float lam = (float)((double)tt / 31.0);
            float px = p0r * lam + p1r * (1.0f - lam) - 0.5f;
            float py = p0c * lam + p1c * (1.0f - lam) - 0.5f;
            float px0 = fminf(fmaxf(floorf(px), 0.0f), 255.0f);
            float py0 = fminf(fmaxf(floorf(py), 0.0f), 255.0f);
            float px1 = fminf(px0 + 1.0f, 255.0f);
            float py1 = fminf(py0 + 1.0f, 255.0f);
            int ix0 = (int)px0, iy0 = (int)py0, ix1 = (int)px1, iy1 = (int)py1;
            float wx1 = px1 - px, wx0 = px - px0;
            float wy1 = py1 - py, wy0 = py - py0;
            float v00 = xb[(size_t)(ix0 * WW + iy0) * 128 + c];
            float v10 = xb[(size_t)(ix1 * WW + iy0) * 128 + c];
            float v01 = xb[(size_t)(ix0 * WW + iy1) * 128 + c];
            float v11 = xb[(size_t)(ix1 * WW + iy1) * 128 + c];
            float v = v00 * (wx1 * wy1) + v10 * (wx0 * wy1)
                    + v01 * (wx1 * wy0) + v11 * (wx0 * wy0);
            mx = fmaxf(mx, v);
        }
        short h = f2bf(mx);
        vh[g] = h;
        vl[g] = f2bf(mx - bf2f(h));
    }
    *(short8_t*)(phi + (size_t)bl * 1024 + c * 8) = vh;
    *(short8_t*)(plo + (size_t)bl * 1024 + c * 8) = vl;
}

// ---------------------------------------------------------------------------
// Kernel 2b: split fp32 weight matrix [1024x1024] into bf16 hi/lo.
// ---------------------------------------------------------------------------
__global__ __launch_bounds__(256) void split_kernel(
    const float* __restrict__ w, short* __restrict__ hi, short* __restrict__ lo)
{
    const int i = (blockIdx.x * 256 + threadIdx.x) * 4;
    float4 v = *(const float4*)(w + i);
    float vv[4] = {v.x, v.y, v.z, v.w};
    short4 h, l;
    short hs[4], ls[4];
#pragma unroll
    for (int j = 0; j < 4; j++) {
        hs[j] = f2bf(vv[j]);
        ls[j] = f2bf(vv[j] - bf2f(hs[j]));
    }
    h.x = hs[0]; h.y = hs[1]; h.z = hs[2]; h.w = hs[3];
    l.x = ls[0]; l.y = ls[1]; l.z = ls[2]; l.w = ls[3];
    *(short4*)(hi + i) = h;
    *(short4*)(lo + i) = l;
}

// ---------------------------------------------------------------------------
// Kernel 3: bf16x3 MFMA GEMM-NT, fused bias+ReLU.
// C[m][n] = relu( sum_k (Ahi+Alo)[m][k]*(Bhi+Blo)[n][k] + bias[n] )
// using hi*hi + lo*hi + hi*lo (drop lo*lo, ~2^-18 rel).
// 128x128 tile, BK=32, 4 waves x (64x64), 16x16x32 MFMA.
// SPLIT_OUT: write bf16 hi/lo pair (for next GEMM); else fp32.
// ---------------------------------------------------------------------------
template <bool SPLIT_OUT>
__global__ __launch_bounds__(256) void gemm_bf16x3(
    const short* __restrict__ Ahi, const short* __restrict__ Alo,
    const short* __restrict__ Bhi, const short* __restrict__ Blo,
    const float* __restrict__ bias,
    float* __restrict__ Cf, short* __restrict__ Chi, short* __restrict__ Clo,
    int M)
{
    // rows padded 32 -> 40 bf16 (80 B): frag ds_read_b128 is <=2-way aliased.
    __shared__ short As_hi[128][40];
    __shared__ short As_lo[128][40];
    __shared__ short Bs_hi[128][40];
    __shared__ short Bs_lo[128][40];

    const int t = threadIdx.x;
    const int tileN = blockIdx.x & 7;       // N=1024 -> 8 tiles; N-major for A reuse in L2
    const int tileM = blockIdx.x >> 3;
    const int m0 = tileM * 128, n0 = tileN * 128;
    const int w = t >> 6, lane = t & 63;
    const int wmb = (w >> 1) * 64, wnb = (w & 1) * 64;
    const int fr = lane & 15;
    const int koff = (lane >> 4) << 3;      // 0,8,16,24

    // staging assignment: 2048 16B-chunks (4 matrices x 128 rows x 4 chunks)
    const short* gsrc[8];
    short* ldst[8];
#pragma unroll
    for (int i = 0; i < 8; i++) {
        int idx = t + (i << 8);
        int c = idx & 511;
        int row = c >> 2;
        int kc = (c & 3) << 3;
        int mat = idx >> 9;
        if (mat == 0) {
            int gr = min(m0 + row, M - 1);
            gsrc[i] = Ahi + (size_t)gr * 1024 + kc; ldst[i] = &As_hi[row][kc];
        } else if (mat == 1) {
            int gr = min(m0 + row, M - 1);
            gsrc[i] = Alo + (size_t)gr * 1024 + kc; ldst[i] = &As_lo[row][kc];
        } else if (mat == 2) {
            gsrc[i] = Bhi + (size_t)(n0 + row) * 1024 + kc; ldst[i] = &Bs_hi[row][kc];
        } else {
            gsrc[i] = Blo + (size_t)(n0 + row) * 1024 + kc; ldst[i] = &Bs_lo[row][kc];
        }
    }

    float4v acc[4][4];
#pragma unroll
    for (int mi = 0; mi < 4; mi++)
#pragma unroll
        for (int ni = 0; ni < 4; ni++)
            acc[mi][ni] = (float4v){0.f, 0.f, 0.f, 0.f};

    for (int k0 = 0; k0 < 1024; k0 += 32) {
#pragma unroll
        for (int i = 0; i < 8; i++) {
            int4 v = *(const int4*)(gsrc[i] + k0);
            *(int4*)(ldst[i]) = v;
        }
        __syncthreads();

        short8_t ah[4], al[4];
#pragma unroll
        for (int mi = 0; mi < 4; mi++) {
            ah[mi] = *(const short8_t*)&As_hi[wmb + mi * 16 + fr][koff];
            al[mi] = *(const short8_t*)&As_lo[wmb + mi * 16 + fr][koff];
        }
#pragma unroll
        for (int ni = 0; ni < 4; ni++) {
            short8_t bh = *(const short8_t*)&Bs_hi[wnb + ni * 16 + fr][koff];
            short8_t bl = *(const short8_t*)&Bs_lo[wnb + ni * 16 + fr][koff];
#pragma unroll
            for (int mi = 0; mi < 4; mi++) {
                acc[mi][ni] = __builtin_amdgcn_mfma_f32_16x16x32_bf16(
                    ah[mi], bh, acc[mi][ni], 0, 0, 0);
                acc[mi][ni] = __builtin_amdgcn_mfma_f32_16x16x32_bf16(
                    al[mi], bh, acc[mi][ni], 0, 0, 0);
                acc[mi][ni] = __builtin_amdgcn_mfma_f32_16x16x32_bf16(
                    ah[mi], bl, acc[mi][ni], 0, 0, 0);
            }
        }
        __syncthreads();
    }

    // epilogue: C/D layout col=lane&15, row=(lane>>4)*4+reg
#pragma unroll
    for (int ni = 0; ni < 4; ni++) {
        int ncol = n0 + wnb + ni * 16 + fr;
        float bv = bias[ncol];
#pragma unroll
        for (int mi = 0; mi < 4; mi++) {
            int r0 = m0 + wmb + mi * 16 + ((lane >> 4) << 2);
#pragma unroll
            for (int i2 = 0; i2 < 4; i2++) {
                int r = r0 + i2;
                if (r < M) {
                    float v = fmaxf(acc[mi][ni][i2] + bv, 0.0f);
                    if (SPLIT_OUT) {
                        short h = f2bf(v);
                        Chi[(size_t)r * 1024 + ncol] = h;
                        Clo[(size_t)r * 1024 + ncol] = f2bf(v - bf2f(h));
                    } else {
                        Cf[(size_t)r * 1024 + ncol] = v;
                    }
                }
            }
        }
    }
}

// ---------------------------------------------------------------------------
// Kernel 4: fc3 (N=4) + softmax + mask + argmax-class key. One wave per line.
// ---------------------------------------------------------------------------
__global__ __launch_bounds__(256) void fc3_softmax_kernel(
    const float* __restrict__ h2, const float* __restrict__ w3,
    const float* __restrict__ b3, float* __restrict__ s, int* __restrict__ keys)
{
    const int m = blockIdx.x * 4 + (threadIdx.x >> 6);
    const int lane = threadIdx.x & 63;
    const float* hp = h2 + (size_t)m * DIM_FC;
    float a0 = 0.f, a1 = 0.f, a2 = 0.f, a3 = 0.f;
    for (int k = lane; k < DIM_FC; k += 64) {
        float hv = hp[k];
        a0 = fmaf(hv, w3[k], a0);
        a1 = fmaf(hv, w3[DIM_FC + k], a1);
        a2 = fmaf(hv, w3[2 * DIM_FC + k], a2);
        a3 = fmaf(hv, w3[3 * DIM_FC + k], a3);
    }
#pragma unroll
    for (int off = 32; off > 0; off >>= 1) {
        a0 += __shfl_down(a0, off, 64);
        a1 += __shfl_down(a1, off, 64);
        a2 += __shfl_down(a2, off, 64);
        a3 += __shfl_down(a3, off, 64);
    }
    if (lane == 0) {
        float l0 = a0 + b3[0], l1 = a1 + b3[1], l2 = a2 + b3[2], l3 = a3 + b3[3];
        float mxl = fmaxf(fmaxf(l0, l1), fmaxf(l2, l3));
        float e0 = expf(l0 - mxl), e1 = expf(l1 - mxl);
        float e2 = expf(l2 - mxl), e3 = expf(l3 - mxl);
        float inv = 1.0f / (e0 + e1 + e2 + e3);
        float s0 = e0 * inv, s1 = e1 * inv, s2 = e2 * inv, s3 = e3 * inv;
        float* sp = s + (size_t)m * 4;
        sp[0] = s0; sp[1] = s1; sp[2] = s2; sp[3] = s3;
        int best = 0; float bv = s0;
        if (s1 > bv) { best = 1; bv = s1; }
        if (s2 > bv) { best = 2; bv = s2; }
        if (s3 > bv) { best = 3; bv = s3; }
        bool msk = ((s1 > 0.25f) || (s2 > 0.25f) || (s3 > 0.25f)) && (s0 < 0.25f);
        keys[m] = msk ? best : -1;
    }
}

// ---------------------------------------------------------------------------
// Kernel 5: stable counting sort by class descending. One wave per batch.
// ---------------------------------------------------------------------------
__global__ __launch_bounds__(64) void order_kernel(
    const int* __restrict__ keys, int* __restrict__ ord, int* __restrict__ cnts)
{
    const int b = blockIdx.x;
    const int lane = threadIdx.x;
    const int* kb = keys + b * LL;
    int c0 = 0, c1 = 0, c2 = 0, c3 = 0;
    for (int line = lane; line < LL; line += 64) {
        int k = kb[line];
        c0 += (k == 0); c1 += (k == 1); c2 += (k == 2); c3 += (k == 3);
    }
#pragma unroll
    for (int off = 32; off > 0; off >>= 1) {
        c0 += __shfl_down(c0, off, 64);
        c1 += __shfl_down(c1, off, 64);
        c2 += __shfl_down(c2, off, 64);
        c3 += __shfl_down(c3, off, 64);
    }
    int t0 = __shfl(c0, 0, 64), t1 = __shfl(c1, 0, 64);
    int t2 = __shfl(c2, 0, 64), t3 = __shfl(c3, 0, 64);
    if (lane == 0) cnts[b] = t0 + t1 + t2 + t3;
    int base[4];
    base[3] = 0; base[2] = t3; base[1] = t3 + t2; base[0] = t3 + t2 + t1;
    int run[4] = {0, 0, 0, 0};
    const unsigned long long below = (1ull << lane) - 1ull;
    int* ob = ord + b * LL;
    for (int s0 = 0; s0 < LL; s0 += 64) {
        int line = s0 + lane;
        int k = (line < LL) ? kb[line] : -2;
#pragma unroll
        for (int kk = 0; kk < 4; kk++) {
            unsigned long long mask = __ballot(k == kk);
            if (k == kk) {
                int pos = base[kk] + run[kk] + __popcll(mask & below);
                ob[pos] = line;
            }
            run[kk] += __popcll(mask);
        }
    }
}

// ---------------------------------------------------------------------------
// Kernel 6: cyclic fill of 2500 outputs per batch.
// ---------------------------------------------------------------------------
__global__ __launch_bounds__(256) void fill_kernel(
    const float* __restrict__ lines, const float* __restrict__ s,
    const int* __restrict__ ord, const int* __restrict__ cnts,
    float* __restrict__ out)
{
    const int i = blockIdx.x * 256 + threadIdx.x;
    if (i >= BB * N_OUT_LINE) return;
    const int b = i / N_OUT_LINE;
    const int j = i % N_OUT_LINE;
    const int cnt = cnts[b];
    float4 lo = {0.f, 0.f, 0.f, 0.f}, sc = {0.f, 0.f, 0.f, 0.f};
    if (cnt > 0) {
        int line = ord[b * LL + (j % cnt)];
        lo = *(const float4*)(lines + ((size_t)b * LL + line) * 4);
        sc = *(const float4*)(s + ((size_t)b * LL + line) * 4);
    }
    *(float4*)(out + (size_t)i * 4) = lo;
    *(float4*)(out + (size_t)(BB * N_OUT_LINE) * 4 + (size_t)i * 4) = sc;
}

// ---------------------------------------------------------------------------
extern "C" void kernel_launch(void* const* d_in, const int* in_sizes, int n_in,
                              void* d_out, int out_size, void* d_ws, size_t ws_size,
                              hipStream_t stream) {
    (void)in_sizes; (void)n_in; (void)out_size; (void)ws_size;
    const float* feature = (const float*)d_in[0];
    const float* lines   = (const float*)d_in[1];
    const float* fc1_w   = (const float*)d_in[2];
    const float* fc1_b   = (const float*)d_in[3];
    const float* w1      = (const float*)d_in[4];
    const float* b1      = (const float*)d_in[5];
    const float* w2      = (const float*)d_in[6];
    const float* b2      = (const float*)d_in[7];
    const float* w3      = (const float*)d_in[8];
    const float* b3      = (const float*)d_in[9];
    float* out = (float*)d_out;

    // workspace (216.6 MB total, same footprint as round 1):
    //   x:       [0, 134,217,728) fp32 NHWC conv output
    //     h1hi/h1lo alias x[0 .. 81,920,000) after sampler
    //     w-splits alias x @ +100 MiB (written after sampler, when x is dead)
    //   pooled_hi/lo: [134,217,728, 216,137,728)  -> h2 (fp32) aliases after GEMM1
    //   s/keys/ord/cnts tail
    float* x = (float*)d_ws;
    short* pooled_hi = (short*)(x + (size_t)BB * PIX * 128);
    short* pooled_lo = pooled_hi + (size_t)MM * DIM_FC;
    short* h1hi = (short*)x;
    short* h1lo = h1hi + (size_t)MM * DIM_FC;
    float* h2 = (float*)pooled_hi;                 // aliases pooled pair exactly
    short* w1hi = (short*)((char*)d_ws + 100u * 1024u * 1024u);
    short* w1lo = w1hi + DIM_FC * DIM_FC;
    short* w2hi = w1lo + DIM_FC * DIM_FC;
    short* w2lo = w2hi + DIM_FC * DIM_FC;
    float* s    = (float*)(pooled_lo + (size_t)MM * DIM_FC);
    int* keys   = (int*)(s + MM * 4);
    int* ord    = keys + MM;
    int* cnts   = ord + MM;

    conv1x1_kernel<<<(BB * PIX) / 128, 256, 0, stream>>>(feature, fc1_w, fc1_b, x);
    sample_pool_kernel<<<MM, 128, 0, stream>>>(lines, x, pooled_hi, pooled_lo);
    // weight splits must run after sampler (they overwrite part of x)
    split_kernel<<<DIM_FC * DIM_FC / 1024, 256, 0, stream>>>(w1, w1hi, w1lo);
    split_kernel<<<DIM_FC * DIM_FC / 1024, 256, 0, stream>>>(w2, w2hi, w2lo);

    const int mtiles = (MM + 127) / 128;           // 157
    gemm_bf16x3<true><<<mtiles * 8, 256, 0, stream>>>(
        pooled_hi, pooled_lo, w1hi, w1lo, b1, nullptr, h1hi, h1lo, MM);
    gemm_bf16x3<false><<<mtiles * 8, 256, 0, stream>>>(
        h1hi, h1lo, w2hi, w2lo, b2, h2, nullptr, nullptr, MM);

    fc3_softmax_kernel<<<MM / 4, 256, 0, stream>>>(h2, w3, b3, s, keys);
    order_kernel<<<BB, 64, 0, stream>>>(keys, ord, cnts);
    fill_kernel<<<(BB * N_OUT_LINE + 255) / 256, 256, 0, stream>>>(
        lines, s, ord, cnts, out);
}

// Round 3
// 966.343 us; speedup vs baseline: 1.7806x; 1.1031x over previous
//
#include <hip/hip_runtime.h>
#include <hip/hip_bf16.h>
#include <math.h>

// Problem constants
#define BB 4
#define C_IN 256
#define HH 256
#define WW 256
#define LL 5000
#define N_PTS0 32
#define N_PTS1 8
#define DIM_LOI 128
#define DIM_FC 1024
#define N_OUT_LINE 2500
#define MM (BB * LL)          // 20000
#define PIX (HH * WW)         // 65536

typedef __attribute__((ext_vector_type(8))) short short8_t;   // 8 bf16 in 4 VGPRs
typedef __attribute__((ext_vector_type(4))) float float4v;

// float -> bf16 (RNE) bit tricks
__device__ __forceinline__ short f2bf(float f) {
    union { float f; unsigned u; } c; c.f = f;
    unsigned u = c.u;
    u += 0x7FFFu + ((u >> 16) & 1u);
    return (short)(u >> 16);
}
__device__ __forceinline__ float bf2f(short h) {
    union { unsigned u; float f; } c; c.u = ((unsigned)(unsigned short)h) << 16;
    return c.f;
}

// ---------------------------------------------------------------------------
// Kernel 1: 1x1 conv as bf16x3 MFMA GEMM.  x[b*PIX+p][o] = feat[b,:,p]·w[o,:]+bias
// M-tile=128 pixels, N=128 outputs (full), K=256 in BK=32 steps.
// feat is [c][p] (K-strided): scalar-dword coalesced loads (lane->pixel),
// inline fp32->bf16 hi/lo split, transpose-on-store to LDS [p][c].
// Memory-bound: 256MB read + 128MB write -> ~61us floor.
// ---------------------------------------------------------------------------
__global__ __launch_bounds__(256) void conv_mfma_kernel(
    const float* __restrict__ feat,   // [B, 256, PIX]
    const short* __restrict__ whi,    // [128, 256] bf16 hi
    const short* __restrict__ wlo,    // [128, 256] bf16 lo
    const float* __restrict__ bias,   // [128]
    float* __restrict__ x)            // [B*PIX, 128]
{
    // pitch 40 shorts (80 B): fragment ds_read_b128 <=2-way aliased (free)
    __shared__ short As_hi[128][40];
    __shared__ short As_lo[128][40];
    __shared__ short Ws_hi[128][40];
    __shared__ short Ws_lo[128][40];

    const int t  = threadIdx.x;
    const int m0 = blockIdx.x * 128;           // global pixel row
    const int b  = m0 >> 16;
    const int p0 = m0 & (PIX - 1);
    const float* fb = feat + (size_t)b * C_IN * PIX + p0;

    const int w = t >> 6, lane = t & 63;
    const int wmb = (w >> 1) * 64, wnb = (w & 1) * 64;
    const int fr = lane & 15;
    const int koff = (lane >> 4) << 3;         // 0,8,16,24

    const int sp = t & 127;                    // staging pixel
    const int cg = t >> 7;                     // staging c-pair group (0/1)

    float4v acc[4][4];
#pragma unroll
    for (int mi = 0; mi < 4; mi++)
#pragma unroll
        for (int ni = 0; ni < 4; ni++)
            acc[mi][ni] = (float4v){0.f, 0.f, 0.f, 0.f};

    for (int k0 = 0; k0 < C_IN; k0 += 32) {
        // W tile: 128 rows x 32 k, hi+lo (pre-split bf16, k-contiguous)
#pragma unroll
        for (int i = 0; i < 2; i++) {
            int idx = t + (i << 8);            // 0..511
            int row = idx >> 2;
            int kc  = (idx & 3) << 3;
            *(int4*)&Ws_hi[row][kc] = *(const int4*)(whi + row * C_IN + k0 + kc);
            *(int4*)&Ws_lo[row][kc] = *(const int4*)(wlo + row * C_IN + k0 + kc);
        }
        // feat tile: 32 c x 128 p; convert+split+transpose inline
#pragma unroll
        for (int j = 0; j < 8; j++) {
            int c = cg * 16 + j * 2;
            float v0 = fb[(size_t)(k0 + c) * PIX + sp];
            float v1 = fb[(size_t)(k0 + c + 1) * PIX + sp];
            short h0 = f2bf(v0), h1 = f2bf(v1);
            short l0 = f2bf(v0 - bf2f(h0)), l1 = f2bf(v1 - bf2f(h1));
            *(unsigned*)&As_hi[sp][c] =
                (unsigned)(unsigned short)h0 | ((unsigned)(unsigned short)h1 << 16);
            *(unsigned*)&As_lo[sp][c] =
                (unsigned)(unsigned short)l0 | ((unsigned)(unsigned short)l1 << 16);
        }
        __syncthreads();

        short8_t ah[4], al[4];
#pragma unroll
        for (int mi = 0; mi < 4; mi++) {
            ah[mi] = *(const short8_t*)&As_hi[wmb + mi * 16 + fr][koff];
            al[mi] = *(const short8_t*)&As_lo[wmb + mi * 16 + fr][koff];
        }
#pragma unroll
        for (int ni = 0; ni < 4; ni++) {
            short8_t bh = *(const short8_t*)&Ws_hi[wnb + ni * 16 + fr][koff];
            short8_t bl = *(const short8_t*)&Ws_lo[wnb + ni * 16 + fr][koff];
#pragma unroll
            for (int mi = 0; mi < 4; mi++) {
                acc[mi][ni] = __builtin_amdgcn_mfma_f32_16x16x32_bf16(
                    ah[mi], bh, acc[mi][ni], 0, 0, 0);
                acc[mi][ni] = __builtin_amdgcn_mfma_f32_16x16x32_bf16(
                    al[mi], bh, acc[mi][ni], 0, 0, 0);
                acc[mi][ni] = __builtin_amdgcn_mfma_f32_16x16x32_bf16(
                    ah[mi], bl, acc[mi][ni], 0, 0, 0);
            }
        }
        __syncthreads();
    }

    // epilogue: C/D layout col=lane&15 (n), row=(lane>>4)*4+reg (m); grid exact
#pragma unroll
    for (int ni = 0; ni < 4; ni++) {
        int ncol = wnb + ni * 16 + fr;
        float bv = bias[ncol];
#pragma unroll
        for (int mi = 0; mi < 4; mi++) {
            int r0 = m0 + wmb + mi * 16 + ((lane >> 4) << 2);
#pragma unroll
            for (int i2 = 0; i2 < 4; i2++) {
                x[(size_t)(r0 + i2) * 128 + ncol] = acc[mi][ni][i2] + bv;
            }
        }
    }
}

// ---------------------------------------------------------------------------
// Kernel 2: bilinear sample + maxpool. Emits bf16 hi/lo split of pooled.
// ---------------------------------------------------------------------------
__global__ __launch_bounds__(128) void sample_pool_kernel(
    const float* __restrict__ lines,   // [B, L, 2, 2]
    const float* __restrict__ x,       // [B*PIX, 128] NHWC
    short* __restrict__ phi,           // [B*L, 1024] bf16 hi
    short* __restrict__ plo)           // [B*L, 1024] bf16 lo
{
    const int bl = blockIdx.x;
    const int b  = bl / LL;
    const int c  = threadIdx.x;
    const float* lp = lines + (size_t)bl * 4;
    const float p0r = lp[0], p0c = lp[1], p1r = lp[2], p1c = lp[3];
    const float* xb = x + (size_t)b * PIX * 128;

    short8_t vh, vl;
#pragma unroll
    for (int g = 0; g < 8; g++) {
        float mx = -INFINITY;
#pragma unroll
        for (int j = 0; j < 4; j++) {
            int tt = g * 4 + j;
            float lam = (float)((double)tt / 31.0);
            float px = p0r * lam + p1r * (1.0f - lam) - 0.5f;
            float py = p0c * lam + p1c * (1.0f - lam) - 0.5f;
            float px0 = fminf(fmaxf(floorf(px), 0.0f), 255.0f);
            float py0 = fminf(fmaxf(floorf(py), 0.0f), 255.0f);
            float px1 = fminf(px0 + 1.0f, 255.0f);
            float py1 = fminf(py0 + 1.0f, 255.0f);
            int ix0 = (int)px0, iy0 = (int)py0, ix1 = (int)px1, iy1 = (int)py1;
            float wx1 = px1 - px, wx0 = px - px0;
            float wy1 = py1 - py, wy0 = py - py0;
            float v00 = xb[(size_t)(ix0 * WW + iy0) * 128 + c];
            float v10 = xb[(size_t)(ix1 * WW + iy0) * 128 + c];
            float v01 = xb[(size_t)(ix0 * WW + iy1) * 128 + c];
            float v11 = xb[(size_t)(ix1 * WW + iy1) * 128 + c];
            float v = v00 * (wx1 * wy1) + v10 * (wx0 * wy1)
                    + v01 * (wx1 * wy0) + v11 * (wx0 * wy0);
            mx = fmaxf(mx, v);
        }
        short h = f2bf(mx);
        vh[g] = h;
        vl[g] = f2bf(mx - bf2f(h));
    }
    *(short8_t*)(phi + (size_t)bl * 1024 + c * 8) = vh;
    *(short8_t*)(plo + (size_t)bl * 1024 + c * 8) = vl;
}

// ---------------------------------------------------------------------------
// Kernel 2b: split fp32 weight matrix into bf16 hi/lo. n4 = elems/4.
// ---------------------------------------------------------------------------
__global__ __launch_bounds__(256) void split_kernel(
    const float* __restrict__ w, short* __restrict__ hi, short* __restrict__ lo)
{
    const int i = (blockIdx.x * 256 + threadIdx.x) * 4;
    float4 v = *(const float4*)(w + i);
    float vv[4] = {v.x, v.y, v.z, v.w};
    short4 h, l;
    short hs[4], ls[4];
#pragma unroll
    for (int j = 0; j < 4; j++) {
        hs[j] = f2bf(vv[j]);
        ls[j] = f2bf(vv[j] - bf2f(hs[j]));
    }
    h.x = hs[0]; h.y = hs[1]; h.z = hs[2]; h.w = hs[3];
    l.x = ls[0]; l.y = ls[1]; l.z = ls[2]; l.w = ls[3];
    *(short4*)(hi + i) = h;
    *(short4*)(lo + i) = l;
}

// ---------------------------------------------------------------------------
// Kernel 3: bf16x3 MFMA GEMM-NT, fused bias+ReLU (MLP layers).
// ---------------------------------------------------------------------------
template <bool SPLIT_OUT>
__global__ __launch_bounds__(256) void gemm_bf16x3(
    const short* __restrict__ Ahi, const short* __restrict__ Alo,
    const short* __restrict__ Bhi, const short* __restrict__ Blo,
    const float* __restrict__ bias,
    float* __restrict__ Cf, short* __restrict__ Chi, short* __restrict__ Clo,
    int M)
{
    __shared__ short As_hi[128][40];
    __shared__ short As_lo[128][40];
    __shared__ short Bs_hi[128][40];
    __shared__ short Bs_lo[128][40];

    const int t = threadIdx.x;
    const int tileN = blockIdx.x & 7;
    const int tileM = blockIdx.x >> 3;
    const int m0 = tileM * 128, n0 = tileN * 128;
    const int w = t >> 6, lane = t & 63;
    const int wmb = (w >> 1) * 64, wnb = (w & 1) * 64;
    const int fr = lane & 15;
    const int koff = (lane >> 4) << 3;

    const short* gsrc[8];
    short* ldst[8];
#pragma unroll
    for (int i = 0; i < 8; i++) {
        int idx = t + (i << 8);
        int c = idx & 511;
        int row = c >> 2;
        int kc = (c & 3) << 3;
        int mat = idx >> 9;
        if (mat == 0) {
            int gr = min(m0 + row, M - 1);
            gsrc[i] = Ahi + (size_t)gr * 1024 + kc; ldst[i] = &As_hi[row][kc];
        } else if (mat == 1) {
            int gr = min(m0 + row, M - 1);
            gsrc[i] = Alo + (size_t)gr * 1024 + kc; ldst[i] = &As_lo[row][kc];
        } else if (mat == 2) {
            gsrc[i] = Bhi + (size_t)(n0 + row) * 1024 + kc; ldst[i] = &Bs_hi[row][kc];
        } else {
            gsrc[i] = Blo + (size_t)(n0 + row) * 1024 + kc; ldst[i] = &Bs_lo[row][kc];
        }
    }

    float4v acc[4][4];
#pragma unroll
    for (int mi = 0; mi < 4; mi++)
#pragma unroll
        for (int ni = 0; ni < 4; ni++)
            acc[mi][ni] = (float4v){0.f, 0.f, 0.f, 0.f};

    for (int k0 = 0; k0 < 1024; k0 += 32) {
#pragma unroll
        for (int i = 0; i < 8; i++) {
            int4 v = *(const int4*)(gsrc[i] + k0);
            *(int4*)(ldst[i]) = v;
        }
        __syncthreads();

        short8_t ah[4], al[4];
#pragma unroll
        for (int mi = 0; mi < 4; mi++) {
            ah[mi] = *(const short8_t*)&As_hi[wmb + mi * 16 + fr][koff];
            al[mi] = *(const short8_t*)&As_lo[wmb + mi * 16 + fr][koff];
        }
#pragma unroll
        for (int ni = 0; ni < 4; ni++) {
            short8_t bh = *(const short8_t*)&Bs_hi[wnb + ni * 16 + fr][koff];
            short8_t bl = *(const short8_t*)&Bs_lo[wnb + ni * 16 + fr][koff];
#pragma unroll
            for (int mi = 0; mi < 4; mi++) {
                acc[mi][ni] = __builtin_amdgcn_mfma_f32_16x16x32_bf16(
                    ah[mi], bh, acc[mi][ni], 0, 0, 0);
                acc[mi][ni] = __builtin_amdgcn_mfma_f32_16x16x32_bf16(
                    al[mi], bh, acc[mi][ni], 0, 0, 0);
                acc[mi][ni] = __builtin_amdgcn_mfma_f32_16x16x32_bf16(
                    ah[mi], bl, acc[mi][ni], 0, 0, 0);
            }
        }
        __syncthreads();
    }

#pragma unroll
    for (int ni = 0; ni < 4; ni++) {
        int ncol = n0 + wnb + ni * 16 + fr;
        float bv = bias[ncol];
#pragma unroll
        for (int mi = 0; mi < 4; mi++) {
            int r0 = m0 + wmb + mi * 16 + ((lane >> 4) << 2);
#pragma unroll
            for (int i2 = 0; i2 < 4; i2++) {
                int r = r0 + i2;
                if (r < M) {
                    float v = fmaxf(acc[mi][ni][i2] + bv, 0.0f);
                    if (SPLIT_OUT) {
                        short h = f2bf(v);
                        Chi[(size_t)r * 1024 + ncol] = h;
                        Clo[(size_t)r * 1024 + ncol] = f2bf(v - bf2f(h));
                    } else {
                        Cf[(size_t)r * 1024 + ncol] = v;
                    }
                }
            }
        }
    }
}

// ---------------------------------------------------------------------------
// Kernel 4: fc3 (N=4) + softmax + mask + argmax-class key. One wave per line.
// ---------------------------------------------------------------------------
__global__ __launch_bounds__(256) void fc3_softmax_kernel(
    const float* __restrict__ h2, const float* __restrict__ w3,
    const float* __restrict__ b3, float* __restrict__ s, int* __restrict__ keys)
{
    const int m = blockIdx.x * 4 + (threadIdx.x >> 6);
    const int lane = threadIdx.x & 63;
    const float* hp = h2 + (size_t)m * DIM_FC;
    float a0 = 0.f, a1 = 0.f, a2 = 0.f, a3 = 0.f;
    for (int k = lane; k < DIM_FC; k += 64) {
        float hv = hp[k];
        a0 = fmaf(hv, w3[k], a0);
        a1 = fmaf(hv, w3[DIM_FC + k], a1);
        a2 = fmaf(hv, w3[2 * DIM_FC + k], a2);
        a3 = fmaf(hv, w3[3 * DIM_FC + k], a3);
    }
#pragma unroll
    for (int off = 32; off > 0; off >>= 1) {
        a0 += __shfl_down(a0, off, 64);
        a1 += __shfl_down(a1, off, 64);
        a2 += __shfl_down(a2, off, 64);
        a3 += __shfl_down(a3, off, 64);
    }
    if (lane == 0) {
        float l0 = a0 + b3[0], l1 = a1 + b3[1], l2 = a2 + b3[2], l3 = a3 + b3[3];
        float mxl = fmaxf(fmaxf(l0, l1), fmaxf(l2, l3));
        float e0 = expf(l0 - mxl), e1 = expf(l1 - mxl);
        float e2 = expf(l2 - mxl), e3 = expf(l3 - mxl);
        float inv = 1.0f / (e0 + e1 + e2 + e3);
        float s0 = e0 * inv, s1 = e1 * inv, s2 = e2 * inv, s3 = e3 * inv;
        float* sp = s + (size_t)m * 4;
        sp[0] = s0; sp[1] = s1; sp[2] = s2; sp[3] = s3;
        int best = 0; float bv = s0;
        if (s1 > bv) { best = 1; bv = s1; }
        if (s2 > bv) { best = 2; bv = s2; }
        if (s3 > bv) { best = 3; bv = s3; }
        bool msk = ((s1 > 0.25f) || (s2 > 0.25f) || (s3 > 0.25f)) && (s0 < 0.25f);
        keys[m] = msk ? best : -1;
    }
}

// ---------------------------------------------------------------------------
// Kernel 5: stable counting sort by class descending. One wave per batch.
// ---------------------------------------------------------------------------
__global__ __launch_bounds__(64) void order_kernel(
    const int* __restrict__ keys, int* __restrict__ ord, int* __restrict__ cnts)
{
    const int b = blockIdx.x;
    const int lane = threadIdx.x;
    const int* kb = keys + b * LL;
    int c0 = 0, c1 = 0, c2 = 0, c3 = 0;
    for (int line = lane; line < LL; line += 64) {
        int k = kb[line];
        c0 += (k == 0); c1 += (k == 1); c2 += (k == 2); c3 += (k == 3);
    }
#pragma unroll
    for (int off = 32; off > 0; off >>= 1) {
        c0 += __shfl_down(c0, off, 64);
        c1 += __shfl_down(c1, off, 64);
        c2 += __shfl_down(c2, off, 64);
        c3 += __shfl_down(c3, off, 64);
    }
    int t0 = __shfl(c0, 0, 64), t1 = __shfl(c1, 0, 64);
    int t2 = __shfl(c2, 0, 64), t3 = __shfl(c3, 0, 64);
    if (lane == 0) cnts[b] = t0 + t1 + t2 + t3;
    int base[4];
    base[3] = 0; base[2] = t3; base[1] = t3 + t2; base[0] = t3 + t2 + t1;
    int run[4] = {0, 0, 0, 0};
    const unsigned long long below = (1ull << lane) - 1ull;
    int* ob = ord + b * LL;
    for (int s0 = 0; s0 < LL; s0 += 64) {
        int line = s0 + lane;
        int k = (line < LL) ? kb[line] : -2;
#pragma unroll
        for (int kk = 0; kk < 4; kk++) {
            unsigned long long mask = __ballot(k == kk);
            if (k == kk) {
                int pos = base[kk] + run[kk] + __popcll(mask & below);
                ob[pos] = line;
            }
            run[kk] += __popcll(mask);
        }
    }
}

// ---------------------------------------------------------------------------
// Kernel 6: cyclic fill of 2500 outputs per batch.
// ---------------------------------------------------------------------------
__global__ __launch_bounds__(256) void fill_kernel(
    const float* __restrict__ lines, const float* __restrict__ s,
    const int* __restrict__ ord, const int* __restrict__ cnts,
    float* __restrict__ out)
{
    const int i = blockIdx.x * 256 + threadIdx.x;
    if (i >= BB * N_OUT_LINE) return;
    const int b = i / N_OUT_LINE;
    const int j = i % N_OUT_LINE;
    const int cnt = cnts[b];
    float4 lo = {0.f, 0.f, 0.f, 0.f}, sc = {0.f, 0.f, 0.f, 0.f};
    if (cnt > 0) {
        int line = ord[b * LL + (j % cnt)];
        lo = *(const float4*)(lines + ((size_t)b * LL + line) * 4);
        sc = *(const float4*)(s + ((size_t)b * LL + line) * 4);
    }
    *(float4*)(out + (size_t)i * 4) = lo;
    *(float4*)(out + (size_t)(BB * N_OUT_LINE) * 4 + (size_t)i * 4) = sc;
}

// ---------------------------------------------------------------------------
extern "C" void kernel_launch(void* const* d_in, const int* in_sizes, int n_in,
                              void* d_out, int out_size, void* d_ws, size_t ws_size,
                              hipStream_t stream) {
    (void)in_sizes; (void)n_in; (void)out_size; (void)ws_size;
    const float* feature = (const float*)d_in[0];
    const float* lines   = (const float*)d_in[1];
    const float* fc1_w   = (const float*)d_in[2];
    const float* fc1_b   = (const float*)d_in[3];
    const float* w1      = (const float*)d_in[4];
    const float* b1      = (const float*)d_in[5];
    const float* w2      = (const float*)d_in[6];
    const float* b2      = (const float*)d_in[7];
    const float* w3      = (const float*)d_in[8];
    const float* b3      = (const float*)d_in[9];
    float* out = (float*)d_out;

    // workspace (~217 MB):
    //   x fp32 NHWC [0, 134.2MB); h1hi/h1lo alias x; w1/w2 splits alias x@+100MiB
    //   pooled_hi/lo [134.2, 216.1MB); h2 aliases pooled
    //   tail: s, keys, ord, cnts, fc1 whi/wlo
    float* x = (float*)d_ws;
    short* pooled_hi = (short*)(x + (size_t)BB * PIX * 128);
    short* pooled_lo = pooled_hi + (size_t)MM * DIM_FC;
    short* h1hi = (short*)x;
    short* h1lo = h1hi + (size_t)MM * DIM_FC;
    float* h2 = (float*)pooled_hi;
    short* w1hi = (short*)((char*)d_ws + 100u * 1024u * 1024u);
    short* w1lo = w1hi + DIM_FC * DIM_FC;
    short* w2hi = w1lo + DIM_FC * DIM_FC;
    short* w2lo = w2hi + DIM_FC * DIM_FC;
    float* s    = (float*)(pooled_lo + (size_t)MM * DIM_FC);
    int* keys   = (int*)(s + MM * 4);
    int* ord    = keys + MM;
    int* cnts   = ord + MM;
    short* fc1hi = (short*)(cnts + 64);            // 32768 shorts
    short* fc1lo = fc1hi + DIM_LOI * C_IN;

    // fc1 weight split must precede conv
    split_kernel<<<(DIM_LOI * C_IN) / 1024, 256, 0, stream>>>(fc1_w, fc1hi, fc1lo);
    conv_mfma_kernel<<<(BB * PIX) / 128, 256, 0, stream>>>(
        feature, fc1hi, fc1lo, fc1_b, x);
    sample_pool_kernel<<<MM, 128, 0, stream>>>(lines, x, pooled_hi, pooled_lo);
    // w1/w2 splits must run after sampler (they overwrite part of x)
    split_kernel<<<DIM_FC * DIM_FC / 1024, 256, 0, stream>>>(w1, w1hi, w1lo);
    split_kernel<<<DIM_FC * DIM_FC / 1024, 256, 0, stream>>>(w2, w2hi, w2lo);

    const int mtiles = (MM + 127) / 128;           // 157
    gemm_bf16x3<true><<<mtiles * 8, 256, 0, stream>>>(
        pooled_hi, pooled_lo, w1hi, w1lo, b1, nullptr, h1hi, h1lo, MM);
    gemm_bf16x3<false><<<mtiles * 8, 256, 0, stream>>>(
        h1hi, h1lo, w2hi, w2lo, b2, h2, nullptr, nullptr, MM);

    fc3_softmax_kernel<<<MM / 4, 256, 0, stream>>>(h2, w3, b3, s, keys);
    order_kernel<<<BB, 64, 0, stream>>>(keys, ord, cnts);
    fill_kernel<<<(BB * N_OUT_LINE + 255) / 256, 256, 0, stream>>>(
        lines, s, ord, cnts, out);
}

// Round 4
// 933.792 us; speedup vs baseline: 1.8427x; 1.0349x over previous
//
#include <hip/hip_runtime.h>
#include <hip/hip_bf16.h>
#include <math.h>

// Problem constants
#define BB 4
#define C_IN 256
#define HH 256
#define WW 256
#define LL 5000
#define N_PTS0 32
#define N_PTS1 8
#define DIM_LOI 128
#define DIM_FC 1024
#define N_OUT_LINE 2500
#define MM (BB * LL)          // 20000
#define PIX (HH * WW)         // 65536

typedef __attribute__((ext_vector_type(8))) short short8_t;   // 8 bf16 in 4 VGPRs
typedef __attribute__((ext_vector_type(4))) float float4v;

// float -> bf16 (RNE) bit tricks
__device__ __forceinline__ short f2bf(float f) {
    union { float f; unsigned u; } c; c.f = f;
    unsigned u = c.u;
    u += 0x7FFFu + ((u >> 16) & 1u);
    return (short)(u >> 16);
}
__device__ __forceinline__ float bf2f(short h) {
    union { unsigned u; float f; } c; c.u = ((unsigned)(unsigned short)h) << 16;
    return c.f;
}

// async global->LDS DMA, 16 B per lane; dest = wave-uniform base + lane*16
__device__ __forceinline__ void load_lds16(const void* g, void* l) {
    __builtin_amdgcn_global_load_lds(
        (const __attribute__((address_space(1))) void*)g,
        (__attribute__((address_space(3))) void*)l, 16, 0, 0);
}

// ---------------------------------------------------------------------------
// Kernel 1: 1x1 conv as bf16x3 MFMA GEMM (unchanged from round 3).
// ---------------------------------------------------------------------------
__global__ __launch_bounds__(256) void conv_mfma_kernel(
    const float* __restrict__ feat,   // [B, 256, PIX]
    const short* __restrict__ whi,    // [128, 256] bf16 hi
    const short* __restrict__ wlo,    // [128, 256] bf16 lo
    const float* __restrict__ bias,   // [128]
    float* __restrict__ x)            // [B*PIX, 128]
{
    __shared__ short As_hi[128][40];
    __shared__ short As_lo[128][40];
    __shared__ short Ws_hi[128][40];
    __shared__ short Ws_lo[128][40];

    const int t  = threadIdx.x;
    const int m0 = blockIdx.x * 128;
    const int b  = m0 >> 16;
    const int p0 = m0 & (PIX - 1);
    const float* fb = feat + (size_t)b * C_IN * PIX + p0;

    const int w = t >> 6, lane = t & 63;
    const int wmb = (w >> 1) * 64, wnb = (w & 1) * 64;
    const int fr = lane & 15;
    const int koff = (lane >> 4) << 3;

    const int sp = t & 127;
    const int cg = t >> 7;

    float4v acc[4][4];
#pragma unroll
    for (int mi = 0; mi < 4; mi++)
#pragma unroll
        for (int ni = 0; ni < 4; ni++)
            acc[mi][ni] = (float4v){0.f, 0.f, 0.f, 0.f};

    for (int k0 = 0; k0 < C_IN; k0 += 32) {
#pragma unroll
        for (int i = 0; i < 2; i++) {
            int idx = t + (i << 8);
            int row = idx >> 2;
            int kc  = (idx & 3) << 3;
            *(int4*)&Ws_hi[row][kc] = *(const int4*)(whi + row * C_IN + k0 + kc);
            *(int4*)&Ws_lo[row][kc] = *(const int4*)(wlo + row * C_IN + k0 + kc);
        }
#pragma unroll
        for (int j = 0; j < 8; j++) {
            int c = cg * 16 + j * 2;
            float v0 = fb[(size_t)(k0 + c) * PIX + sp];
            float v1 = fb[(size_t)(k0 + c + 1) * PIX + sp];
            short h0 = f2bf(v0), h1 = f2bf(v1);
            short l0 = f2bf(v0 - bf2f(h0)), l1 = f2bf(v1 - bf2f(h1));
            *(unsigned*)&As_hi[sp][c] =
                (unsigned)(unsigned short)h0 | ((unsigned)(unsigned short)h1 << 16);
            *(unsigned*)&As_lo[sp][c] =
                (unsigned)(unsigned short)l0 | ((unsigned)(unsigned short)l1 << 16);
        }
        __syncthreads();

        short8_t ah[4], al[4];
#pragma unroll
        for (int mi = 0; mi < 4; mi++) {
            ah[mi] = *(const short8_t*)&As_hi[wmb + mi * 16 + fr][koff];
            al[mi] = *(const short8_t*)&As_lo[wmb + mi * 16 + fr][koff];
        }
#pragma unroll
        for (int ni = 0; ni < 4; ni++) {
            short8_t bh = *(const short8_t*)&Ws_hi[wnb + ni * 16 + fr][koff];
            short8_t bl = *(const short8_t*)&Ws_lo[wnb + ni * 16 + fr][koff];
#pragma unroll
            for (int mi = 0; mi < 4; mi++) {
                acc[mi][ni] = __builtin_amdgcn_mfma_f32_16x16x32_bf16(
                    ah[mi], bh, acc[mi][ni], 0, 0, 0);
                acc[mi][ni] = __builtin_amdgcn_mfma_f32_16x16x32_bf16(
                    al[mi], bh, acc[mi][ni], 0, 0, 0);
                acc[mi][ni] = __builtin_amdgcn_mfma_f32_16x16x32_bf16(
                    ah[mi], bl, acc[mi][ni], 0, 0, 0);
            }
        }
        __syncthreads();
    }

#pragma unroll
    for (int ni = 0; ni < 4; ni++) {
        int ncol = wnb + ni * 16 + fr;
        float bv = bias[ncol];
#pragma unroll
        for (int mi = 0; mi < 4; mi++) {
            int r0 = m0 + wmb + mi * 16 + ((lane >> 4) << 2);
#pragma unroll
            for (int i2 = 0; i2 < 4; i2++) {
                x[(size_t)(r0 + i2) * 128 + ncol] = acc[mi][ni][i2] + bv;
            }
        }
    }
}

// ---------------------------------------------------------------------------
// Kernel 2: bilinear sample + maxpool -> bf16 hi/lo pooled (unchanged).
// ---------------------------------------------------------------------------
__global__ __launch_bounds__(128) void sample_pool_kernel(
    const float* __restrict__ lines,
    const float* __restrict__ x,
    short* __restrict__ phi,
    short* __restrict__ plo)
{
    const int bl = blockIdx.x;
    const int b  = bl / LL;
    const int c  = threadIdx.x;
    const float* lp = lines + (size_t)bl * 4;
    const float p0r = lp[0], p0c = lp[1], p1r = lp[2], p1c = lp[3];
    const float* xb = x + (size_t)b * PIX * 128;

    short8_t vh, vl;
#pragma unroll
    for (int g = 0; g < 8; g++) {
        float mx = -INFINITY;
#pragma unroll
        for (int j = 0; j < 4; j++) {
            int tt = g * 4 + j;
            float lam = (float)((double)tt / 31.0);
            float px = p0r * lam + p1r * (1.0f - lam) - 0.5f;
            float py = p0c * lam + p1c * (1.0f - lam) - 0.5f;
            float px0 = fminf(fmaxf(floorf(px), 0.0f), 255.0f);
            float py0 = fminf(fmaxf(floorf(py), 0.0f), 255.0f);
            float px1 = fminf(px0 + 1.0f, 255.0f);
            float py1 = fminf(py0 + 1.0f, 255.0f);
            int ix0 = (int)px0, iy0 = (int)py0, ix1 = (int)px1, iy1 = (int)py1;
            float wx1 = px1 - px, wx0 = px - px0;
            float wy1 = py1 - py, wy0 = py - py0;
            float v00 = xb[(size_t)(ix0 * WW + iy0) * 128 + c];
            float v10 = xb[(size_t)(ix1 * WW + iy0) * 128 + c];
            float v01 = xb[(size_t)(ix0 * WW + iy1) * 128 + c];
            float v11 = xb[(size_t)(ix1 * WW + iy1) * 128 + c];
            float v = v00 * (wx1 * wy1) + v10 * (wx0 * wy1)
                    + v01 * (wx1 * wy0) + v11 * (wx0 * wy0);
            mx = fmaxf(mx, v);
        }
        short h = f2bf(mx);
        vh[g] = h;
        vl[g] = f2bf(mx - bf2f(h));
    }
    *(short8_t*)(phi + (size_t)bl * 1024 + c * 8) = vh;
    *(short8_t*)(plo + (size_t)bl * 1024 + c * 8) = vl;
}

// ---------------------------------------------------------------------------
// Kernel 2b: split fp32 weights into bf16 hi/lo (unchanged).
// ---------------------------------------------------------------------------
__global__ __launch_bounds__(256) void split_kernel(
    const float* __restrict__ w, short* __restrict__ hi, short* __restrict__ lo)
{
    const int i = (blockIdx.x * 256 + threadIdx.x) * 4;
    float4 v = *(const float4*)(w + i);
    float vv[4] = {v.x, v.y, v.z, v.w};
    short4 h, l;
    short hs[4], ls[4];
#pragma unroll
    for (int j = 0; j < 4; j++) {
        hs[j] = f2bf(vv[j]);
        ls[j] = f2bf(vv[j] - bf2f(hs[j]));
    }
    h.x = hs[0]; h.y = hs[1]; h.z = hs[2]; h.w = hs[3];
    l.x = ls[0]; l.y = ls[1]; l.z = ls[2]; l.w = ls[3];
    *(short4*)(hi + i) = h;
    *(short4*)(lo + i) = l;
}

// ---------------------------------------------------------------------------
// Kernel 3: bf16x3 MFMA GEMM-NT v2.
//  - async global->LDS DMA staging (global_load_lds width=16), m97 structure
//  - unpadded [128][32] LDS (lane-contiguous for DMA; reads are even 8/bank)
//  - XCD-aware tile map: all 8 N-tiles of an M-panel on one XCD
// 32 KB LDS/block. Wave w stages matrix w (0:Ahi 1:Alo 2:Bhi 3:Blo).
// ---------------------------------------------------------------------------
template <bool SPLIT_OUT>
__global__ __launch_bounds__(256) void gemm_bf16x3(
    const short* __restrict__ Ahi, const short* __restrict__ Alo,
    const short* __restrict__ Bhi, const short* __restrict__ Blo,
    const float* __restrict__ bias,
    float* __restrict__ Cf, short* __restrict__ Chi, short* __restrict__ Clo,
    int M)
{
    __shared__ short lds[4][128 * 32];

    const int t = threadIdx.x;
    const int blk = blockIdx.x;
    // blk%8 selects XCD; keep tileM fixed per XCD across the 8 N-tiles
    const int tileM = (blk & 7) | ((blk >> 6) << 3);
    const int tileN = (blk >> 3) & 7;
    if (tileM * 128 >= M) return;
    const int m0 = tileM * 128, n0 = tileN * 128;
    const int w = t >> 6, lane = t & 63;
    const int wmb = (w >> 1) * 64, wnb = (w & 1) * 64;
    const int fr = lane & 15;
    const int koff = (lane >> 4) << 3;

    // DMA assignment: wave w -> matrix w, 8 chunks of 1 KB (16 rows x 32 k)
    const short* mats[4] = {Ahi, Alo, Bhi, Blo};
    const short* gp[8];
    void* lp[8];
#pragma unroll
    for (int i = 0; i < 8; i++) {
        int row = i * 16 + (lane >> 2);
        int kc  = (lane & 3) * 8;
        int grow = (w < 2) ? min(m0 + row, M - 1) : (n0 + row);
        gp[i] = mats[w] + (size_t)grow * 1024 + kc;
        lp[i] = &lds[w][i * 512 + lane * 8];
    }

    float4v acc[4][4];
#pragma unroll
    for (int mi = 0; mi < 4; mi++)
#pragma unroll
        for (int ni = 0; ni < 4; ni++)
            acc[mi][ni] = (float4v){0.f, 0.f, 0.f, 0.f};

    for (int k0 = 0; k0 < 1024; k0 += 32) {
#pragma unroll
        for (int i = 0; i < 8; i++) {
            load_lds16(gp[i], lp[i]);
            gp[i] += 32;
        }
        __syncthreads();   // drains DMA (vmcnt) + joins waves

        short8_t ah[4], al[4];
#pragma unroll
        for (int mi = 0; mi < 4; mi++) {
            int r = wmb + mi * 16 + fr;
            ah[mi] = *(const short8_t*)&lds[0][r * 32 + koff];
            al[mi] = *(const short8_t*)&lds[1][r * 32 + koff];
        }
#pragma unroll
        for (int ni = 0; ni < 4; ni++) {
            int r = wnb + ni * 16 + fr;
            short8_t bh = *(const short8_t*)&lds[2][r * 32 + koff];
            short8_t bl = *(const short8_t*)&lds[3][r * 32 + koff];
#pragma unroll
            for (int mi = 0; mi < 4; mi++) {
                acc[mi][ni] = __builtin_amdgcn_mfma_f32_16x16x32_bf16(
                    ah[mi], bh, acc[mi][ni], 0, 0, 0);
                acc[mi][ni] = __builtin_amdgcn_mfma_f32_16x16x32_bf16(
                    al[mi], bh, acc[mi][ni], 0, 0, 0);
                acc[mi][ni] = __builtin_amdgcn_mfma_f32_16x16x32_bf16(
                    ah[mi], bl, acc[mi][ni], 0, 0, 0);
            }
        }
        __syncthreads();   // protect LDS from next iteration's DMA
    }

#pragma unroll
    for (int ni = 0; ni < 4; ni++) {
        int ncol = n0 + wnb + ni * 16 + fr;
        float bv = bias[ncol];
#pragma unroll
        for (int mi = 0; mi < 4; mi++) {
            int r0 = m0 + wmb + mi * 16 + ((lane >> 4) << 2);
#pragma unroll
            for (int i2 = 0; i2 < 4; i2++) {
                int r = r0 + i2;
                if (r < M) {
                    float v = fmaxf(acc[mi][ni][i2] + bv, 0.0f);
                    if (SPLIT_OUT) {
                        short h = f2bf(v);
                        Chi[(size_t)r * 1024 + ncol] = h;
                        Clo[(size_t)r * 1024 + ncol] = f2bf(v - bf2f(h));
                    } else {
                        Cf[(size_t)r * 1024 + ncol] = v;
                    }
                }
            }
        }
    }
}

// ---------------------------------------------------------------------------
// Kernel 4: fc3 (N=4) + softmax + mask + argmax-class key (unchanged).
// ---------------------------------------------------------------------------
__global__ __launch_bounds__(256) void fc3_softmax_kernel(
    const float* __restrict__ h2, const float* __restrict__ w3,
    const float* __restrict__ b3, float* __restrict__ s, int* __restrict__ keys)
{
    const int m = blockIdx.x * 4 + (threadIdx.x >> 6);
    const int lane = threadIdx.x & 63;
    const float* hp = h2 + (size_t)m * DIM_FC;
    float a0 = 0.f, a1 = 0.f, a2 = 0.f, a3 = 0.f;
    for (int k = lane; k < DIM_FC; k += 64) {
        float hv = hp[k];
        a0 = fmaf(hv, w3[k], a0);
        a1 = fmaf(hv, w3[DIM_FC + k], a1);
        a2 = fmaf(hv, w3[2 * DIM_FC + k], a2);
        a3 = fmaf(hv, w3[3 * DIM_FC + k], a3);
    }
#pragma unroll
    for (int off = 32; off > 0; off >>= 1) {
        a0 += __shfl_down(a0, off, 64);
        a1 += __shfl_down(a1, off, 64);
        a2 += __shfl_down(a2, off, 64);
        a3 += __shfl_down(a3, off, 64);
    }
    if (lane == 0) {
        float l0 = a0 + b3[0], l1 = a1 + b3[1], l2 = a2 + b3[2], l3 = a3 + b3[3];
        float mxl = fmaxf(fmaxf(l0, l1), fmaxf(l2, l3));
        float e0 = expf(l0 - mxl), e1 = expf(l1 - mxl);
        float e2 = expf(l2 - mxl), e3 = expf(l3 - mxl);
        float inv = 1.0f / (e0 + e1 + e2 + e3);
        float s0 = e0 * inv, s1 = e1 * inv, s2 = e2 * inv, s3 = e3 * inv;
        float* sp = s + (size_t)m * 4;
        sp[0] = s0; sp[1] = s1; sp[2] = s2; sp[3] = s3;
        int best = 0; float bv = s0;
        if (s1 > bv) { best = 1; bv = s1; }
        if (s2 > bv) { best = 2; bv = s2; }
        if (s3 > bv) { best = 3; bv = s3; }
        bool msk = ((s1 > 0.25f) || (s2 > 0.25f) || (s3 > 0.25f)) && (s0 < 0.25f);
        keys[m] = msk ? best : -1;
    }
}

// ---------------------------------------------------------------------------
// Kernel 5: stable counting sort by class descending (unchanged).
// ---------------------------------------------------------------------------
__global__ __launch_bounds__(64) void order_kernel(
    const int* __restrict__ keys, int* __restrict__ ord, int* __restrict__ cnts)
{
    const int b = blockIdx.x;
    const int lane = threadIdx.x;
    const int* kb = keys + b * LL;
    int c0 = 0, c1 = 0, c2 = 0, c3 = 0;
    for (int line = lane; line < LL; line += 64) {
        int k = kb[line];
        c0 += (k == 0); c1 += (k == 1); c2 += (k == 2); c3 += (k == 3);
    }
#pragma unroll
    for (int off = 32; off > 0; off >>= 1) {
        c0 += __shfl_down(c0, off, 64);
        c1 += __shfl_down(c1, off, 64);
        c2 += __shfl_down(c2, off, 64);
        c3 += __shfl_down(c3, off, 64);
    }
    int t0 = __shfl(c0, 0, 64), t1 = __shfl(c1, 0, 64);
    int t2 = __shfl(c2, 0, 64), t3 = __shfl(c3, 0, 64);
    if (lane == 0) cnts[b] = t0 + t1 + t2 + t3;
    int base[4];
    base[3] = 0; base[2] = t3; base[1] = t3 + t2; base[0] = t3 + t2 + t1;
    int run[4] = {0, 0, 0, 0};
    const unsigned long long below = (1ull << lane) - 1ull;
    int* ob = ord + b * LL;
    for (int s0 = 0; s0 < LL; s0 += 64) {
        int line = s0 + lane;
        int k = (line < LL) ? kb[line] : -2;
#pragma unroll
        for (int kk = 0; kk < 4; kk++) {
            unsigned long long mask = __ballot(k == kk);
            if (k == kk) {
                int pos = base[kk] + run[kk] + __popcll(mask & below);
                ob[pos] = line;
            }
            run[kk] += __popcll(mask);
        }
    }
}

// ---------------------------------------------------------------------------
// Kernel 6: cyclic fill of 2500 outputs per batch (unchanged).
// ---------------------------------------------------------------------------
__global__ __launch_bounds__(256) void fill_kernel(
    const float* __restrict__ lines, const float* __restrict__ s,
    const int* __restrict__ ord, const int* __restrict__ cnts,
    float* __restrict__ out)
{
    const int i = blockIdx.x * 256 + threadIdx.x;
    if (i >= BB * N_OUT_LINE) return;
    const int b = i / N_OUT_LINE;
    const int j = i % N_OUT_LINE;
    const int cnt = cnts[b];
    float4 lo = {0.f, 0.f, 0.f, 0.f}, sc = {0.f, 0.f, 0.f, 0.f};
    if (cnt > 0) {
        int line = ord[b * LL + (j % cnt)];
        lo = *(const float4*)(lines + ((size_t)b * LL + line) * 4);
        sc = *(const float4*)(s + ((size_t)b * LL + line) * 4);
    }
    *(float4*)(out + (size_t)i * 4) = lo;
    *(float4*)(out + (size_t)(BB * N_OUT_LINE) * 4 + (size_t)i * 4) = sc;
}

// ---------------------------------------------------------------------------
extern "C" void kernel_launch(void* const* d_in, const int* in_sizes, int n_in,
                              void* d_out, int out_size, void* d_ws, size_t ws_size,
                              hipStream_t stream) {
    (void)in_sizes; (void)n_in; (void)out_size; (void)ws_size;
    const float* feature = (const float*)d_in[0];
    const float* lines   = (const float*)d_in[1];
    const float* fc1_w   = (const float*)d_in[2];
    const float* fc1_b   = (const float*)d_in[3];
    const float* w1      = (const float*)d_in[4];
    const float* b1      = (const float*)d_in[5];
    const float* w2      = (const float*)d_in[6];
    const float* b2      = (const float*)d_in[7];
    const float* w3      = (const float*)d_in[8];
    const float* b3      = (const float*)d_in[9];
    float* out = (float*)d_out;

    float* x = (float*)d_ws;
    short* pooled_hi = (short*)(x + (size_t)BB * PIX * 128);
    short* pooled_lo = pooled_hi + (size_t)MM * DIM_FC;
    short* h1hi = (short*)x;
    short* h1lo = h1hi + (size_t)MM * DIM_FC;
    float* h2 = (float*)pooled_hi;
    short* w1hi = (short*)((char*)d_ws + 100u * 1024u * 1024u);
    short* w1lo = w1hi + DIM_FC * DIM_FC;
    short* w2hi = w1lo + DIM_FC * DIM_FC;
    short* w2lo = w2hi + DIM_FC * DIM_FC;
    float* s    = (float*)(pooled_lo + (size_t)MM * DIM_FC);
    int* keys   = (int*)(s + MM * 4);
    int* ord    = keys + MM;
    int* cnts   = ord + MM;
    short* fc1hi = (short*)(cnts + 64);
    short* fc1lo = fc1hi + DIM_LOI * C_IN;

    split_kernel<<<(DIM_LOI * C_IN) / 1024, 256, 0, stream>>>(fc1_w, fc1hi, fc1lo);
    conv_mfma_kernel<<<(BB * PIX) / 128, 256, 0, stream>>>(
        feature, fc1hi, fc1lo, fc1_b, x);
    sample_pool_kernel<<<MM, 128, 0, stream>>>(lines, x, pooled_hi, pooled_lo);
    split_kernel<<<DIM_FC * DIM_FC / 1024, 256, 0, stream>>>(w1, w1hi, w1lo);
    split_kernel<<<DIM_FC * DIM_FC / 1024, 256, 0, stream>>>(w2, w2hi, w2lo);

    // grid: 20 M-panel groups x 64 (8 XCD-slots x 8 N-tiles); tail blocks exit
    const int mgroups = (((MM + 127) / 128) + 7) / 8;   // 20
    gemm_bf16x3<true><<<mgroups * 64, 256, 0, stream>>>(
        pooled_hi, pooled_lo, w1hi, w1lo, b1, nullptr, h1hi, h1lo, MM);
    gemm_bf16x3<false><<<mgroups * 64, 256, 0, stream>>>(
        h1hi, h1lo, w2hi, w2lo, b2, h2, nullptr, nullptr, MM);

    fc3_softmax_kernel<<<MM / 4, 256, 0, stream>>>(h2, w3, b3, s, keys);
    order_kernel<<<BB, 64, 0, stream>>>(keys, ord, cnts);
    fill_kernel<<<(BB * N_OUT_LINE + 255) / 256, 256, 0, stream>>>(
        lines, s, ord, cnts, out);
}